// Round 1
// baseline (213.745 us; speedup 1.0000x reference)
//
#include <hip/hip_runtime.h>
#include <math.h>

// CaLCS soft-LCS DP.
// B=20 batches, L=20 length, V=100000 vocab.
// Only 8000 elements of topic_prob are ever read (gather by hard_label),
// then a 21x21 DP per batch. One block, one launch.

#define CB 20
#define CL 20
#define CV 100000

__global__ __launch_bounds__(256) void calcs_kernel(
    const float* __restrict__ topic_prob,   // [B, L, V] fp32
    const int*   __restrict__ hard_label,   // [B, L] int32
    float*       __restrict__ out)          // [1] fp32
{
    __shared__ int   s_hl[CB * CL];          // raw labels
    __shared__ float s_P[CB * CL * CL];      // gathered P[b][j][k]
    __shared__ float s_calc[CB];             // per-batch loss

    const int tid = threadIdx.x;

    // ---- stage labels into LDS ----
    for (int t = tid; t < CB * CL; t += blockDim.x) s_hl[t] = hard_label[t];
    __syncthreads();

    // ---- cooperative gather: P[b][j][k] = topic_prob[b, j, clip(hl[b,k], 0, V-1)] ----
    for (int t = tid; t < CB * CL * CL; t += blockDim.x) {
        int b   = t / (CL * CL);
        int rem = t - b * (CL * CL);
        int j   = rem / CL;
        int k   = rem - j * CL;
        int hl  = s_hl[b * CL + k];
        int idx = hl < 0 ? 0 : (hl > CV - 1 ? CV - 1 : hl);
        s_P[t] = topic_prob[(size_t)b * ((size_t)CL * CV) + (size_t)j * CV + (size_t)idx];
    }
    __syncthreads();

    // ---- per-batch serial DP (thread b handles batch b) ----
    if (tid < CB) {
        const int b = tid;

        // mask / len (mask[k] lives in registers; only constant-indexed below)
        float maskv[CL];
        int len = 0;
        #pragma unroll
        for (int k = 0; k < CL; ++k) {
            bool m = (s_hl[b * CL + k] >= 0);
            maskv[k] = m ? 1.0f : 0.0f;
            len += m ? 1 : 0;
        }

        float prev[CL + 1];
        float curr[CL + 1];
        #pragma unroll
        for (int kk = 0; kk <= CL; ++kk) prev[kk] = 0.0f;

        float final_v = 0.0f;  // dp[0][0] covers len==0 case
        const float* Pb = &s_P[b * CL * CL];

        for (int j = 0; j < CL; ++j) {
            // mj via LDS (dynamic j) to avoid dynamic register-array indexing
            float mj = (s_hl[b * CL + j] >= 0) ? 1.0f : 0.0f;
            float c = 0.0f;    // carry: dp[j+1][k] (left neighbor)
            curr[0] = 0.0f;
            #pragma unroll
            for (int k = 0; k < CL; ++k) {
                float p   = Pb[j * CL + k];
                float val = p * (prev[k] + 1.0f) + (1.0f - p) * fmaxf(c, prev[k + 1]);
                val = (mj * maskv[k] > 0.0f) ? val : 0.0f;
                c = val;
                curr[k + 1] = val;
            }
            // capture dp[len][len] when we've just produced row (j+1)
            bool cap = (j + 1 == len);
            #pragma unroll
            for (int kk = 0; kk <= CL; ++kk) {
                if (cap && kk == len) final_v = curr[kk];
                prev[kk] = curr[kk];
            }
        }

        s_calc[b] = -logf(final_v / (float)len);
    }
    __syncthreads();

    // ---- reduce to scalar ----
    if (tid == 0) {
        float s = 0.0f;
        #pragma unroll
        for (int b = 0; b < CB; ++b) s += s_calc[b];
        out[0] = s / (float)CB;
    }
}

extern "C" void kernel_launch(void* const* d_in, const int* in_sizes, int n_in,
                              void* d_out, int out_size, void* d_ws, size_t ws_size,
                              hipStream_t stream) {
    const float* topic_prob = (const float*)d_in[0];
    const int*   hard_label = (const int*)d_in[1];
    float*       out        = (float*)d_out;
    calcs_kernel<<<1, 256, 0, stream>>>(topic_prob, hard_label, out);
}

// Round 2
// 212.911 us; speedup vs baseline: 1.0039x; 1.0039x over previous
//
#include <hip/hip_runtime.h>
#include <math.h>

// CaLCS soft-LCS DP.  B=20, L=20, V=100000.
// Only 8000 elements of topic_prob are read (gather by hard_label), then a
// 21x21 DP per batch.  One block, one launch.
//
// R2 changes vs R1:
//  - 1024-thread block; each thread issues 8 INDEPENDENT gather loads into
//    registers (one ~900-cycle latency exposure instead of ~31 serialized).
//  - DP uses in-place row update (diag temp) + 20-bit mask bitset: register
//    state drops from ~62 to ~25 floats.
//  - Wave-0 shuffle reduction replaces LDS reduction (one less barrier).

#define CB 20
#define CL 20
#define CV 100000
#define NT 1024
#define NP (CB * CL * CL)          // 8000 gathered elements
#define PER ((NP + NT - 1) / NT)   // 8 loads per thread

__global__ __launch_bounds__(NT) void calcs_kernel(
    const float* __restrict__ topic_prob,   // [B, L, V] fp32
    const int*   __restrict__ hard_label,   // [B, L] int32
    float*       __restrict__ out)          // [1] fp32
{
    __shared__ int   s_hl[CB * CL];
    __shared__ float s_P[NP];

    const int tid = threadIdx.x;

    // ---- stage labels ----
    if (tid < CB * CL) s_hl[tid] = hard_label[tid];
    __syncthreads();

    // ---- gather: 8 independent loads per thread, then LDS writes ----
    float vals[PER];
    #pragma unroll
    for (int i = 0; i < PER; ++i) {
        int t  = tid + i * NT;
        int tt = t < NP ? t : 0;           // clamp (masked out on store)
        int b   = tt / (CL * CL);
        int rem = tt - b * (CL * CL);
        int j   = rem / CL;
        int k   = rem - j * CL;
        int hl  = s_hl[b * CL + k];
        int ci  = hl < 0 ? 0 : (hl > CV - 1 ? CV - 1 : hl);
        vals[i] = topic_prob[(size_t)(b * CL + j) * CV + (size_t)ci];
    }
    #pragma unroll
    for (int i = 0; i < PER; ++i) {
        int t = tid + i * NT;
        if (t < NP) s_P[t] = vals[i];
    }
    __syncthreads();

    // ---- per-batch serial DP: thread b (all in wave 0) handles batch b ----
    float loss = 0.0f;
    if (tid < CB) {
        const int b = tid;

        unsigned mbits = 0;
        #pragma unroll
        for (int k = 0; k < CL; ++k)
            mbits |= (s_hl[b * CL + k] >= 0 ? 1u : 0u) << k;
        const int len = __popc(mbits);

        float prev[CL + 1];
        #pragma unroll
        for (int kk = 0; kk <= CL; ++kk) prev[kk] = 0.0f;

        float final_v = 0.0f;              // dp[0][0] covers len==0
        const float* Pb = &s_P[b * CL * CL];

        for (int j = 0; j < CL; ++j) {
            const bool mj = (mbits >> j) & 1u;
            float c = 0.0f;                // left neighbor in new row
            float d = prev[0];             // diag = old row [k]
            float row_end = 0.0f;
            #pragma unroll
            for (int k = 0; k < CL; ++k) {
                float p = Pb[j * CL + k];
                float u = prev[k + 1];     // up = old row [k+1]
                float val = p * (d + 1.0f) + (1.0f - p) * fmaxf(c, u);
                bool mk = (mbits >> k) & 1u;
                val = (mj && mk) ? val : 0.0f;
                d = u;                      // old row value saved before...
                prev[k + 1] = val;          // ...overwriting with new row
                c = val;
                if (k + 1 == len) row_end = val;   // k is compile-time const
            }
            if (j + 1 == len) final_v = row_end;
        }
        loss = -logf(final_v / (float)len);
    }

    // ---- wave-0 shuffle reduction (lanes >= 20 hold 0) ----
    if (tid < 64) {
        #pragma unroll
        for (int off = 32; off > 0; off >>= 1)
            loss += __shfl_down(loss, off, 64);
        if (tid == 0) out[0] = loss / (float)CB;
    }
}

extern "C" void kernel_launch(void* const* d_in, const int* in_sizes, int n_in,
                              void* d_out, int out_size, void* d_ws, size_t ws_size,
                              hipStream_t stream) {
    const float* topic_prob = (const float*)d_in[0];
    const int*   hard_label = (const int*)d_in[1];
    float*       out        = (float*)d_out;
    calcs_kernel<<<1, NT, 0, stream>>>(topic_prob, hard_label, out);
}